// Round 8
// baseline (1337.039 us; speedup 1.0000x reference)
//
#include <hip/hip_runtime.h>

#define DEVI __device__ __forceinline__

typedef __attribute__((ext_vector_type(8))) __bf16 bf16x8;
typedef __attribute__((ext_vector_type(4))) float f32x4;
typedef unsigned short u16;
typedef unsigned int u32;

static constexpr int kB = 32;
static constexpr int kL = 3137;           // 56*56+1
static constexpr int kM = kB * kL;        // 100384 rows total
static constexpr int kHeads = 12;
static constexpr float kScale = 0.17677669529663687f;  // 32^-0.5
static constexpr int kNC = 13;            // CLS key chunks of 256 (13*256 >= 3137)

DEVI u16 f2b(float f) {                   // f32 -> bf16 RNE
  u32 u = __float_as_uint(f);
  u32 r = (u + 0x7fffu + ((u >> 16) & 1u)) >> 16;
  return (u16)r;
}
DEVI float blo(u32 u) { return __uint_as_float(u << 16); }
DEVI float bhi(u32 u) { return __uint_as_float(u & 0xffff0000u); }
DEVI float b2f(u16 h) { return __uint_as_float(((u32)h) << 16); }

DEVI void async16(const void* g, void* l) {
  __builtin_amdgcn_global_load_lds((const __attribute__((address_space(1))) u32*)g,
                                   (__attribute__((address_space(3))) u32*)l, 16, 0, 0);
}

DEVI float wred_max(float v) {
#pragma unroll
  for (int o = 32; o; o >>= 1) v = fmaxf(v, __shfl_xor(v, o));
  return v;
}
DEVI float wred_sum(float v) {
#pragma unroll
  for (int o = 32; o; o >>= 1) v += __shfl_xor(v, o);
  return v;
}

// ---------------- weight f32 -> bf16 ----------------
__global__ void cvt_bf16(const float* __restrict__ in, u16* __restrict__ out, int n) {
  int i = blockIdx.x * 256 + threadIdx.x;
  if (i < n) out[i] = f2b(in[i]);
}

// ---------------- LayerNorm over 384: 4 rows/block, wave per row, float2 vec ----------------
__global__ __launch_bounds__(256)
void ln384(const float* __restrict__ x, const float* __restrict__ gam,
           const float* __restrict__ bet, u16* __restrict__ out, int rows) {
  int row = blockIdx.x * 4 + (threadIdx.x >> 6);
  if (row >= rows) return;
  int lane = threadIdx.x & 63;
  const float2* xr = (const float2*)(x + (size_t)row * 384);
  float2 v[3];
  float s = 0.f, s2 = 0.f;
#pragma unroll
  for (int i = 0; i < 3; i++) {
    v[i] = xr[lane + 64 * i];
    s += v[i].x + v[i].y;
    s2 += v[i].x * v[i].x + v[i].y * v[i].y;
  }
  s = wred_sum(s);
  s2 = wred_sum(s2);
  float mean = s * (1.f / 384.f);
  float var = s2 * (1.f / 384.f) - mean * mean;
  float rinv = rsqrtf(var + 1e-5f);
  const float2* gp = (const float2*)gam;
  const float2* bp = (const float2*)bet;
  u32* orow = (u32*)(out + (size_t)row * 384);
#pragma unroll
  for (int i = 0; i < 3; i++) {
    int idx = lane + 64 * i;
    float2 gg = gp[idx], bb = bp[idx];
    float lo = (v[i].x - mean) * rinv * gg.x + bb.x;
    float hi = (v[i].y - mean) * rinv * gg.y + bb.y;
    orow[idx] = (u32)f2b(lo) | ((u32)f2b(hi) << 16);
  }
}

DEVI float gelu_exact(float v) { return 0.5f * v * (1.f + erff(v * 0.70710678118654752f)); }

// ---------------- bf16 MFMA GEMM, BARRIER-FREE per-wave:  out = A @ W^T + bias [+res] ----
// Block = 4 independent waves. Wave w owns a 64x64 tile at (row0 + w*64, colw).
// A: private per-wave LDS, 3 buffers x 4KB (48KB/block, 3 blocks/CU), staged via
//    global_load_lds, per-wave counted vmcnt (no s_barrier anywhere in the loop).
// B: straight global->register loads (weights are L2-resident), depth-1 rotating
//    prefetch, manually 2x-unrolled with named bwA/bwB (rule 20).
// Hazard ledger (per wave, program order): buffer (kt+2)%3 staged at iter kt was
//   last ds_read at iter kt-1, whose reads completed before MFMA(kt-1) (lgkm wait)
//   -> no WAR. vmcnt: in-flight at top of iter kt = A(kt+1)[4] + B(kt)[4] worst
//   case = 8 -> vmcnt(8) guarantees A(kt) landed; tail iters use vmcnt(4).
// Swizzle (proven pair, 0-conflict): store granule (lane&3)^((lane>>3)&3),
//   read granule g^((c>>1)&3)  [row%16 = lane>>2 on store, = c on read].
// EPI: 0 = bias -> bf16 ; 1 = bias + res -> f32 ; 2 = bias + gelu -> bf16
template <int EPI>
__global__ __launch_bounds__(256, 3)
void gemm_bt(const u16* __restrict__ A, const u16* __restrict__ W,
             const float* __restrict__ bias, const float* __restrict__ res,
             void* __restrict__ outp, int M, int N, int K, int NX) {
  // T1: bijective XCD swizzle (m204) on flattened 1D grid; NX = N/64 col strips
  const int nwg = gridDim.x;
  const int orig = blockIdx.x;
  const int xcd = orig & 7, rest = orig >> 3;
  const int q8 = nwg >> 3, r8 = nwg & 7;
  const int id = ((xcd < r8) ? xcd * (q8 + 1) : r8 * (q8 + 1) + (xcd - r8) * q8) + rest;
  const int colw = (id % NX) * 64, row0 = (id / NX) * 256;

  const int tid = threadIdx.x, lane = tid & 63, wv = tid >> 6;
  const int c = lane & 15, g = lane >> 4;
  const int rowW = row0 + wv * 64;                     // this wave's row base

  __shared__ __align__(16) u16 Albs[4][3][2048];       // [wave][buf][64 rows x 32 u16]
  u16* Ab = &Albs[wv][0][0];

  f32x4 acc[4][4];
  f32x4 zero = {0.f, 0.f, 0.f, 0.f};
#pragma unroll
  for (int m = 0; m < 4; m++)
#pragma unroll
    for (int n = 0; n < 4; n++) acc[m][n] = zero;

  // A staging: 4 gload_lds per K-step; instr i covers rows i*16 + (lane>>2).
  const int rr = lane >> 2;
  const int gsrc = (lane & 3) ^ ((lane >> 3) & 3);     // proven source pre-swizzle
  const u16* baseA[4];
#pragma unroll
  for (int i = 0; i < 4; i++)
    baseA[i] = A + (size_t)min(rowW + i * 16 + rr, M - 1) * K + gsrc * 8;

  auto stageA = [&](int kt, int buf) {
    int off = kt * 32;
#pragma unroll
    for (int i = 0; i < 4; i++)
      async16(baseA[i] + off, Ab + buf * 2048 + i * 512);
  };

  // B register loads: frag n = B[colw + n*16 + c][kt*32 + g*8 ..] (L2-resident)
  const u16* baseB = W + (size_t)(colw + c) * K + g * 8;
  auto loadB = [&](int kt, bf16x8* bw) {
#pragma unroll
    for (int n = 0; n < 4; n++)
      bw[n] = *(const bf16x8*)(baseB + (size_t)(n * 16) * K + kt * 32);
  };

  const int axor = ((g ^ ((c >> 1) & 3)) << 3);        // proven read swizzle
  auto rdA = [&](int buf, bf16x8* af) {
#pragma unroll
    for (int m = 0; m < 4; m++)
      af[m] = *(const bf16x8*)&Ab[buf * 2048 + (m * 16 + c) * 32 + axor];
  };

  const int NT = K >> 5;                               // 12 or 48 (always even)
  stageA(0, 0);
  stageA(1, 1);
  bf16x8 bwA[4], bwB[4];
  loadB(0, bwA);

  for (int kt = 0; kt < NT; kt += 2) {
    // ---- even iter: uses A buf kt%3, B in bwA ----
    asm volatile("s_waitcnt vmcnt(8)" ::: "memory");   // A(kt) landed
    bf16x8 af[4];
    rdA(kt % 3, af);
    if (kt + 2 < NT) stageA(kt + 2, (kt + 2) % 3);
    loadB(kt + 1, bwB);
    __builtin_amdgcn_s_setprio(1);
#pragma unroll
    for (int m = 0; m < 4; m++)
#pragma unroll
      for (int n = 0; n < 4; n++)
        acc[m][n] = __builtin_amdgcn_mfma_f32_16x16x32_bf16(af[m], bwA[n], acc[m][n], 0, 0, 0);
    __builtin_amdgcn_s_setprio(0);

    // ---- odd iter: uses A buf (kt+1)%3, B in bwB ----
    if (kt + 3 < NT) asm volatile("s_waitcnt vmcnt(8)" ::: "memory");
    else             asm volatile("s_waitcnt vmcnt(4)" ::: "memory");  // tail: force A(NT-1)
    bf16x8 af2[4];
    rdA((kt + 1) % 3, af2);
    if (kt + 3 < NT) stageA(kt + 3, (kt + 3) % 3);
    if (kt + 2 < NT) loadB(kt + 2, bwA);
    __builtin_amdgcn_s_setprio(1);
#pragma unroll
    for (int m = 0; m < 4; m++)
#pragma unroll
      for (int n = 0; n < 4; n++)
        acc[m][n] = __builtin_amdgcn_mfma_f32_16x16x32_bf16(af2[m], bwB[n], acc[m][n], 0, 0, 0);
    __builtin_amdgcn_s_setprio(0);
  }

  int cc[4];
  float bv[4];
#pragma unroll
  for (int n = 0; n < 4; n++) {
    cc[n] = colw + n * 16 + c;
    bv[n] = bias[cc[n]];
  }
#pragma unroll
  for (int m = 0; m < 4; m++) {
    int rb = rowW + m * 16 + (g << 2);
#pragma unroll
    for (int j = 0; j < 4; j++) {
      int r = rb + j;
      if (r < M) {
#pragma unroll
        for (int n = 0; n < 4; n++) {
          float vv = acc[m][n][j] + bv[n];
          size_t off = (size_t)r * N + cc[n];
          if constexpr (EPI == 0) {
            ((u16*)outp)[off] = f2b(vv);
          } else if constexpr (EPI == 1) {
            ((float*)outp)[off] = vv + res[off];
          } else {
            ((u16*)outp)[off] = f2b(gelu_exact(vv));
          }
        }
      }
    }
  }
}

// ---------------- CLS attention, flash-decode phase 1 ----------------
__global__ __launch_bounds__(256)
void cls_part(const u16* __restrict__ qkv, float* __restrict__ parts) {
  int bh = blockIdx.x;
  int chunk = blockIdx.y;
  int b = bh / kHeads, h = bh % kHeads;
  __shared__ float qs[32];
  __shared__ float ps[256];
  __shared__ float red[8];
  __shared__ float part[8][32];
  int tid = threadIdx.x, lane = tid & 63, wv = tid >> 6;
  size_t rb = (size_t)b * kL;
  if (tid < 32) qs[tid] = b2f(qkv[rb * 1152 + h * 32 + tid]) * kScale;
  __syncthreads();
  int t0 = chunk * 256;
  int nTok = min(256, kL - t0);
  float s = -1e30f;
  if (tid < nTok) {
    const u16* kp = qkv + (rb + t0 + tid) * 1152 + 384 + h * 32;
    s = 0.f;
#pragma unroll
    for (int g4 = 0; g4 < 4; g4++) {
      uint4 u = *(const uint4*)(kp + g4 * 8);
      s += qs[g4*8+0]*blo(u.x) + qs[g4*8+1]*bhi(u.x)
         + qs[g4*8+2]*blo(u.y) + qs[g4*8+3]*bhi(u.y)
         + qs[g4*8+4]*blo(u.z) + qs[g4*8+5]*bhi(u.z)
         + qs[g4*8+6]*blo(u.w) + qs[g4*8+7]*bhi(u.w);
    }
  }
  float m = wred_max(s);
  if (lane == 0) red[wv] = m;
  __syncthreads();
  float gm = fmaxf(fmaxf(red[0], red[1]), fmaxf(red[2], red[3]));
  float p = (tid < nTok) ? __expf(s - gm) : 0.f;
  ps[tid] = p;
  float ls = wred_sum(p);
  if (lane == 0) red[4 + wv] = ls;
  __syncthreads();
  float tot = red[4] + red[5] + red[6] + red[7];
  int d = tid & 31, g = tid >> 5;
  float a = 0.f;
  for (int t = g; t < nTok; t += 8)
    a += ps[t] * b2f(qkv[(rb + t0 + t) * 1152 + 768 + h * 32 + d]);
  part[g][d] = a;
  __syncthreads();
  if (tid < 32) {
    float o = 0.f;
#pragma unroll
    for (int g2 = 0; g2 < 8; g2++) o += part[g2][tid];
    float* pp = parts + ((size_t)bh * kNC + chunk) * 34;
    pp[2 + tid] = o;
    if (tid == 0) { pp[0] = gm; pp[1] = tot; }
  }
}

// ---------------- CLS attention, phase 2: LSE-merge 13 chunks ----------------
__global__ __launch_bounds__(64)
void cls_reduce(const float* __restrict__ parts, u16* __restrict__ aout) {
  int bh = blockIdx.x;
  int b = bh / kHeads, h = bh % kHeads;
  int tid = threadIdx.x;
  __shared__ float sm[kNC], ss[kNC];
  if (tid < kNC) {
    sm[tid] = parts[((size_t)bh * kNC + tid) * 34];
    ss[tid] = parts[((size_t)bh * kNC + tid) * 34 + 1];
  }
  __syncthreads();
  float M = -1e30f;
#pragma unroll
  for (int c = 0; c < kNC; c++) M = fmaxf(M, sm[c]);
  float W = 0.f;
#pragma unroll
  for (int c = 0; c < kNC; c++) W += ss[c] * __expf(sm[c] - M);
  if (tid < 32) {
    float o = 0.f;
#pragma unroll
    for (int c = 0; c < kNC; c++)
      o += parts[((size_t)bh * kNC + c) * 34 + 2 + tid] * __expf(sm[c] - M);
    aout[(size_t)b * kL * 384 + h * 32 + tid] = f2b(o / W);
  }
}

// ---------------- precompute bias_full[class][head][k][q] (64x64 per pair) ----------------
__global__ __launch_bounds__(256)
void bias_pre(const float* __restrict__ relb, float* __restrict__ bf) {
  int blk = blockIdx.x;           // cls*12 + h
  int cls = blk / 12, h = blk % 12;
  int clsH = (cls >> 1) & 1, clsW = cls & 1;
  for (int idx = threadIdx.x; idx < 4096; idx += 256) {
    int k = idx >> 6, q = idx & 63;
    float v = 0.f;
    if (k >= 50) {
      v = -1e9f;
    } else if (k >= 1 && q < 49) {
      int kt = k - 1, ki = kt / 7, kj = kt % 7;
      int qi = q / 7, qj = q % 7;
      v = relb[((qi - ki + 6) * 13 + (qj - kj + 6)) * 12 + h];
      int rq = (clsH ? (qi < 4 ? 1 : 2) : 0) * 3 + (clsW ? (qj < 4 ? 1 : 2) : 0);
      int rk = (clsH ? (ki < 4 ? 1 : 2) : 0) * 3 + (clsW ? (kj < 4 ? 1 : 2) : 0);
      if (rq != rk) v -= 100.f;
    }
    bf[(size_t)blk * 4096 + idx] = v;
  }
}

// ---------------- shifted-window attention, MFMA version ----------------
__global__ __launch_bounds__(256)
void win_attn2(const u16* __restrict__ qkv, const float* __restrict__ biasf,
               u16* __restrict__ aout) {
  const int tid = threadIdx.x, lane = tid & 63, wv = tid >> 6;
  const int gid = blockIdx.x * 4 + wv;
  const int h = gid % 12;
  const int wr = gid / 12;        // 0..2047
  const int win = wr & 63, b = wr >> 6;
  const int wi = win >> 3, wj = win & 7;
  const int cls = ((wi == 7) ? 2 : 0) + ((wj == 7) ? 1 : 0);
  const int c = lane & 15, g = lane >> 4;

  __shared__ __align__(16) u16 KS[4][64 * 40];   // K row-major, row stride 40 u16 (80B)
  __shared__ __align__(16) u16 VT[4][32 * 72];   // V transposed [d][tok], stride 72 u16
  __shared__ int RW[4][52];
  u16* Ks = KS[wv];
  u16* Vt = VT[wv];
  int* Rows = RW[wv];

#pragma unroll
  for (int it = 0; it < 2; ++it) {
    int idx = it * 64 + lane;
    int tok = idx >> 1, half = idx & 1;
    if (tok < 50) {
      int row;
      if (tok == 0) {
        row = b * kL;                                  // CLS
      } else {
        int n = tok - 1;
        int i = n / 7, j = n % 7;
        int r = wi * 7 + i, c2 = wj * 7 + j;           // rolled-canvas coords
        int orr = r + 3; if (orr >= 56) orr -= 56;     // original coords
        int occ = c2 + 3; if (occ >= 56) occ -= 56;
        row = b * kL + 1 + orr * 56 + occ;
      }
      if (half == 0) Rows[tok] = row;
      const u16* base = qkv + (size_t)row * 1152 + h * 32 + half * 16;
      uint4 k0 = *(const uint4*)(base + 384);
      uint4 k1 = *(const uint4*)(base + 384 + 8);
      *(uint4*)&Ks[tok * 40 + half * 16] = k0;
      *(uint4*)&Ks[tok * 40 + half * 16 + 8] = k1;
      uint4 v0 = *(const uint4*)(base + 768);
      uint4 v1 = *(const uint4*)(base + 768 + 8);
      u32 vw[8] = {v0.x, v0.y, v0.z, v0.w, v1.x, v1.y, v1.z, v1.w};
#pragma unroll
      for (int m = 0; m < 8; ++m) {
        Vt[(half * 16 + m * 2 + 0) * 72 + tok] = (u16)(vw[m] & 0xffffu);
        Vt[(half * 16 + m * 2 + 1) * 72 + tok] = (u16)(vw[m] >> 16);
      }
    } else {
      uint4 z = {0u, 0u, 0u, 0u};
      *(uint4*)&Ks[tok * 40 + half * 16] = z;
      *(uint4*)&Ks[tok * 40 + half * 16 + 8] = z;
#pragma unroll
      for (int m = 0; m < 16; ++m) Vt[(half * 16 + m) * 72 + tok] = 0;
    }
  }
  __syncthreads();

  bf16x8 qf[4];
#pragma unroll
  for (int nt = 0; nt < 4; ++nt) {
    int q = nt * 16 + c;
    if (q > 48) q = 48;
    const u16* qp = qkv + (size_t)Rows[q + 1] * 1152 + h * 32 + g * 8;
    qf[nt] = *(const bf16x8*)qp;
  }

  f32x4 s[4][4];
  {
    f32x4 z = {0.f, 0.f, 0.f, 0.f};
    bf16x8 kf[4];
#pragma unroll
    for (int mt = 0; mt < 4; ++mt)
      kf[mt] = *(const bf16x8*)&Ks[(mt * 16 + c) * 40 + g * 8];
#pragma unroll
    for (int mt = 0; mt < 4; ++mt)
#pragma unroll
      for (int nt = 0; nt < 4; ++nt)
        s[mt][nt] = __builtin_amdgcn_mfma_f32_16x16x32_bf16(kf[mt], qf[nt], z, 0, 0, 0);
  }

  const float* bp = biasf + (size_t)(cls * 12 + h) * 4096;
  u32 wq[4][8];
#pragma unroll
  for (int nt = 0; nt < 4; ++nt) {
    float pv[16];
#pragma unroll
    for (int mt = 0; mt < 4; ++mt)
#pragma unroll
      for (int r = 0; r < 4; ++r)
        pv[mt * 4 + r] = s[mt][nt][r] * kScale + bp[(mt * 16 + g * 4 + r) * 64 + nt * 16 + c];
    float mx = pv[0];
#pragma unroll
    for (int i2 = 1; i2 < 16; ++i2) mx = fmaxf(mx, pv[i2]);
    mx = fmaxf(mx, __shfl_xor(mx, 16));
    mx = fmaxf(mx, __shfl_xor(mx, 32));
    float sum = 0.f;
#pragma unroll
    for (int i2 = 0; i2 < 16; ++i2) { pv[i2] = __expf(pv[i2] - mx); sum += pv[i2]; }
    sum += __shfl_xor(sum, 16);
    sum += __shfl_xor(sum, 32);
    float rs = 1.f / sum;
#pragma unroll
    for (int i2 = 0; i2 < 16; ++i2) pv[i2] *= rs;
#pragma unroll
    for (int mt = 0; mt < 4; ++mt) {
      u32 w0, w1;
      asm("v_cvt_pk_bf16_f32 %0, %1, %2" : "=v"(w0) : "v"(pv[mt * 4 + 0]), "v"(pv[mt * 4 + 1]));
      asm("v_cvt_pk_bf16_f32 %0, %1, %2" : "=v"(w1) : "v"(pv[mt * 4 + 2]), "v"(pv[mt * 4 + 3]));
      wq[nt][mt * 2 + 0] = w0;
      wq[nt][mt * 2 + 1] = w1;
    }
  }

  bf16x8 pa[4][2];
#pragma unroll
  for (int mt2 = 0; mt2 < 4; ++mt2)
#pragma unroll
    for (int ks = 0; ks < 2; ++ks) {
      union { u32 u[4]; bf16x8 v; } cvt;
#pragma unroll
      for (int wj2 = 0; wj2 < 4; ++wj2) {
        int srcLane = c + 16 * (((g & 1) << 1) + (wj2 >> 1));
        u32 a0 = (u32)__shfl((int)wq[mt2][(2 * ks + 0) * 2 + (wj2 & 1)], srcLane);
        u32 a1 = (u32)__shfl((int)wq[mt2][(2 * ks + 1) * 2 + (wj2 & 1)], srcLane);
        cvt.u[wj2] = (g < 2) ? a0 : a1;
      }
      pa[mt2][ks] = cvt.v;
    }

  f32x4 o[4][2];
  f32x4 z2 = {0.f, 0.f, 0.f, 0.f};
#pragma unroll
  for (int mt2 = 0; mt2 < 4; ++mt2)
#pragma unroll
    for (int ntd = 0; ntd < 2; ++ntd) o[mt2][ntd] = z2;
#pragma unroll
  for (int ks = 0; ks < 2; ++ks) {
    bf16x8 vf[2];
#pragma unroll
    for (int ntd = 0; ntd < 2; ++ntd)
      vf[ntd] = *(const bf16x8*)&Vt[(ntd * 16 + c) * 72 + ks * 32 + g * 8];
#pragma unroll
    for (int mt2 = 0; mt2 < 4; ++mt2)
#pragma unroll
      for (int ntd = 0; ntd < 2; ++ntd)
        o[mt2][ntd] = __builtin_amdgcn_mfma_f32_16x16x32_bf16(pa[mt2][ks], vf[ntd], o[mt2][ntd], 0, 0, 0);
  }

#pragma unroll
  for (int mt2 = 0; mt2 < 4; ++mt2)
#pragma unroll
    for (int r = 0; r < 4; ++r) {
      int q = mt2 * 16 + g * 4 + r;
      if (q < 49) {
        int row = Rows[q + 1];
        u16* op = aout + (size_t)row * 384 + h * 32 + c;
        op[0]  = f2b(o[mt2][0][r]);
        op[16] = f2b(o[mt2][1][r]);
      }
    }
}

// ---------------- launcher ----------------
extern "C" void kernel_launch(void* const* d_in, const int* in_sizes, int n_in,
                              void* d_out, int out_size, void* d_ws, size_t ws_size,
                              hipStream_t stream) {
  const float* x      = (const float*)d_in[0];
  const float* n1g    = (const float*)d_in[1];
  const float* n1b    = (const float*)d_in[2];
  const float* qkv_w  = (const float*)d_in[3];
  const float* qkv_b  = (const float*)d_in[4];
  const float* relb   = (const float*)d_in[5];
  const float* proj_w = (const float*)d_in[6];
  const float* proj_b = (const float*)d_in[7];
  const float* n2g    = (const float*)d_in[8];
  const float* n2b    = (const float*)d_in[9];
  const float* fc1_w  = (const float*)d_in[10];
  const float* fc1_b  = (const float*)d_in[11];
  const float* fc2_w  = (const float*)d_in[12];
  const float* fc2_b  = (const float*)d_in[13];
  float* out = (float*)d_out;
  char* ws = (char*)d_ws;

  // workspace layout (total ~312 MB); x1 lives in d_out
  u16* wqkv  = (u16*)(ws + 0);                       //  884,736 B (dead after qkv GEMM)
  float* biasf = (float*)(ws + 0);                   //  786,432 B (reuses wqkv region)
  u16* wproj = (u16*)(ws + 884736);                  //  294,912 B
  u16* wfc1  = (u16*)(ws + 1179648);                 // 1,179,648 B
  u16* wfc2  = (u16*)(ws + 2359296);                 // 1,179,648 B
  u16* qkvb  = (u16*)(ws + 3538944);                 // 231,284,736 B (dead after attention)
  u16* h2b   = (u16*)(ws + 3538944);                 // reuse: LN2 chunk out (38.5 MB)
  u16* gb    = (u16*)(ws + 3538944 + 41943040);      // reuse: fc1 chunk out (154.2 MB)
  u16* hbuf  = (u16*)(ws + 234823680);               // 77,094,912 B (h, then attn_out)
  float* parts = (float*)d_out;                      // CLS partials: dead-until-proj d_out

  cvt_bf16<<<dim3((442368 + 255) / 256), 256, 0, stream>>>(qkv_w, wqkv, 442368);
  cvt_bf16<<<dim3((147456 + 255) / 256), 256, 0, stream>>>(proj_w, wproj, 147456);
  cvt_bf16<<<dim3((589824 + 255) / 256), 256, 0, stream>>>(fc1_w, wfc1, 589824);
  cvt_bf16<<<dim3((589824 + 255) / 256), 256, 0, stream>>>(fc2_w, wfc2, 589824);

  ln384<<<(kM + 3) / 4, 256, 0, stream>>>(x, n1g, n1b, hbuf, kM);
  gemm_bt<0><<<393 * 18, 256, 0, stream>>>(hbuf, wqkv, qkv_b, nullptr, qkvb, kM, 1152, 384, 18);
  bias_pre<<<48, 256, 0, stream>>>(relb, biasf);     // into dead wqkv region
  cls_part<<<dim3(kB * kHeads, kNC), 256, 0, stream>>>(qkvb, parts);
  cls_reduce<<<kB * kHeads, 64, 0, stream>>>(parts, hbuf);
  win_attn2<<<kB * 64 * kHeads / 4, 256, 0, stream>>>(qkvb, biasf, hbuf);
  gemm_bt<1><<<393 * 6, 256, 0, stream>>>(hbuf, wproj, proj_b, x, out, kM, 384, 384, 6);

  for (int c = 0; c < 2; c++) {
    int r0 = c * 50192, nr = 50192;
    ln384<<<(nr + 3) / 4, 256, 0, stream>>>(out + (size_t)r0 * 384, n2g, n2b, h2b, nr);
    gemm_bt<2><<<197 * 24, 256, 0, stream>>>(h2b, wfc1, fc1_b, nullptr, gb, nr, 1536, 384, 24);
    gemm_bt<1><<<197 * 6, 256, 0, stream>>>(gb, wfc2, fc2_b, out + (size_t)r0 * 384,
                                            out + (size_t)r0 * 384, nr, 384, 1536, 6);
  }
}

// Round 9
// 1017.606 us; speedup vs baseline: 1.3139x; 1.3139x over previous
//
#include <hip/hip_runtime.h>

#define DEVI __device__ __forceinline__

typedef __attribute__((ext_vector_type(8))) __bf16 bf16x8;
typedef __attribute__((ext_vector_type(4))) float f32x4;
typedef unsigned short u16;
typedef unsigned int u32;

static constexpr int kB = 32;
static constexpr int kL = 3137;           // 56*56+1
static constexpr int kM = kB * kL;        // 100384 rows total
static constexpr int kHeads = 12;
static constexpr float kScale = 0.17677669529663687f;  // 32^-0.5
static constexpr int kNC = 13;            // CLS key chunks of 256 (13*256 >= 3137)

DEVI u16 f2b(float f) {                   // f32 -> bf16 RNE
  u32 u = __float_as_uint(f);
  u32 r = (u + 0x7fffu + ((u >> 16) & 1u)) >> 16;
  return (u16)r;
}
DEVI float blo(u32 u) { return __uint_as_float(u << 16); }
DEVI float bhi(u32 u) { return __uint_as_float(u & 0xffff0000u); }
DEVI float b2f(u16 h) { return __uint_as_float(((u32)h) << 16); }

DEVI void async16(const void* g, void* l) {
  __builtin_amdgcn_global_load_lds((const __attribute__((address_space(1))) u32*)g,
                                   (__attribute__((address_space(3))) u32*)l, 16, 0, 0);
}

DEVI float wred_max(float v) {
#pragma unroll
  for (int o = 32; o; o >>= 1) v = fmaxf(v, __shfl_xor(v, o));
  return v;
}
DEVI float wred_sum(float v) {
#pragma unroll
  for (int o = 32; o; o >>= 1) v += __shfl_xor(v, o);
  return v;
}

// ---------------- weight f32 -> bf16 ----------------
__global__ void cvt_bf16(const float* __restrict__ in, u16* __restrict__ out, int n) {
  int i = blockIdx.x * 256 + threadIdx.x;
  if (i < n) out[i] = f2b(in[i]);
}

// ---------------- LayerNorm over 384: 4 rows/block, wave per row, float2 vec ----------------
__global__ __launch_bounds__(256)
void ln384(const float* __restrict__ x, const float* __restrict__ gam,
           const float* __restrict__ bet, u16* __restrict__ out, int rows) {
  int row = blockIdx.x * 4 + (threadIdx.x >> 6);
  if (row >= rows) return;
  int lane = threadIdx.x & 63;
  const float2* xr = (const float2*)(x + (size_t)row * 384);
  float2 v[3];
  float s = 0.f, s2 = 0.f;
#pragma unroll
  for (int i = 0; i < 3; i++) {
    v[i] = xr[lane + 64 * i];
    s += v[i].x + v[i].y;
    s2 += v[i].x * v[i].x + v[i].y * v[i].y;
  }
  s = wred_sum(s);
  s2 = wred_sum(s2);
  float mean = s * (1.f / 384.f);
  float var = s2 * (1.f / 384.f) - mean * mean;
  float rinv = rsqrtf(var + 1e-5f);
  const float2* gp = (const float2*)gam;
  const float2* bp = (const float2*)bet;
  u32* orow = (u32*)(out + (size_t)row * 384);
#pragma unroll
  for (int i = 0; i < 3; i++) {
    int idx = lane + 64 * i;
    float2 gg = gp[idx], bb = bp[idx];
    float lo = (v[i].x - mean) * rinv * gg.x + bb.x;
    float hi = (v[i].y - mean) * rinv * gg.y + bb.y;
    orow[idx] = (u32)f2b(lo) | ((u32)f2b(hi) << 16);
  }
}

DEVI float gelu_exact(float v) { return 0.5f * v * (1.f + erff(v * 0.70710678118654752f)); }

// ---------------- bf16 MFMA GEMM (benched-best R3/R4 structure) ----------------
// 128x128 tile, BK=32, 4 waves (2x2), 4x4 frags of 16x16x32 per wave.
// Triple-buffered LDS + counted vmcnt(4) across raw barriers, proven zero-conflict
// swizzle pair, T1 bijective XCD grid swizzle, T5 setprio around MFMA cluster.
// EPI: 0 = bias -> bf16 ; 1 = bias + res -> f32 ; 2 = bias + gelu -> bf16
template <int EPI>
__global__ __launch_bounds__(256)
void gemm_bt(const u16* __restrict__ A, const u16* __restrict__ W,
             const float* __restrict__ bias, const float* __restrict__ res,
             void* __restrict__ outp, int M, int N, int K, int NX) {
  // T1: bijective XCD swizzle (m204) on flattened 1D grid
  const int nwg = gridDim.x;
  const int orig = blockIdx.x;
  const int xcd = orig & 7, rest = orig >> 3;
  const int q8 = nwg >> 3, r8 = nwg & 7;
  const int id = ((xcd < r8) ? xcd * (q8 + 1) : r8 * (q8 + 1) + (xcd - r8) * q8) + rest;
  const int col0 = (id % NX) * 128, row0 = (id / NX) * 128;

  const int tid = threadIdx.x, lane = tid & 63, wv = tid >> 6;
  __shared__ __align__(16) u16 As[3][128 * 32];
  __shared__ __align__(16) u16 Bs[3][128 * 32];
  f32x4 acc[4][4];
  f32x4 zero = {0.f, 0.f, 0.f, 0.f};
#pragma unroll
  for (int m = 0; m < 4; m++)
#pragma unroll
    for (int n = 0; n < 4; n++) acc[m][n] = zero;
  const int wm = wv >> 1, wn = wv & 1;
  const int c = lane & 15, g = lane >> 4;
  const int NT = K >> 5;

  // staging: LDS linear (wave-uniform base + lane*16); global source granule
  // pre-permuted by the PROVEN swizzle (lane&3)^((lane>>3)&3)  [0-conflict, R4].
  auto stage = [&](int kt, int bfi) {
#pragma unroll
    for (int s = 0; s < 2; s++) {
      int ch = wv * 2 + s;                       // 8 chunks of 16 rows x 64B
      int r = ch * 16 + (lane >> 2);
      int gnat = (lane & 3) ^ ((lane >> 3) & 3); // source pre-swizzle
      int kk = kt * 32 + gnat * 8;
      const u16* gp = A + (size_t)min(row0 + r, M - 1) * K + kk;
      async16(gp, &As[bfi][ch * 512]);
      const u16* gq = W + (size_t)min(col0 + r, N - 1) * K + kk;
      async16(gq, &Bs[bfi][ch * 512]);
    }
  };

  stage(0, 0);                                   // 4 loads
  stage(1, 1);                                   // 8 outstanding
  int cur = 0;
  for (int kt = 0; kt < NT; ++kt) {
    if (kt + 1 < NT) asm volatile("s_waitcnt vmcnt(4)" ::: "memory");
    else             asm volatile("s_waitcnt vmcnt(0)" ::: "memory");
    __builtin_amdgcn_s_barrier();                // all waves' tile-kt loads landed
    if (kt + 2 < NT) {
      int nb = cur + 2; if (nb >= 3) nb -= 3;
      stage(kt + 2, nb);                         // overwrites tile kt-1's buffer (safe)
    }
    bf16x8 af[4], bw[4];
#pragma unroll
    for (int m = 0; m < 4; m++) {
      int row = wm * 64 + m * 16 + c;
      af[m] = *(const bf16x8*)&As[cur][row * 32 + ((g ^ ((row >> 1) & 3)) << 3)];
    }
#pragma unroll
    for (int n = 0; n < 4; n++) {
      int row = wn * 64 + n * 16 + c;
      bw[n] = *(const bf16x8*)&Bs[cur][row * 32 + ((g ^ ((row >> 1) & 3)) << 3)];
    }
    __builtin_amdgcn_s_setprio(1);
#pragma unroll
    for (int m = 0; m < 4; m++)
#pragma unroll
      for (int n = 0; n < 4; n++)
        acc[m][n] = __builtin_amdgcn_mfma_f32_16x16x32_bf16(af[m], bw[n], acc[m][n], 0, 0, 0);
    __builtin_amdgcn_s_setprio(0);
    cur = cur + 1; if (cur >= 3) cur -= 3;
  }

  int cc[4];
  float bv[4];
#pragma unroll
  for (int n = 0; n < 4; n++) {
    cc[n] = col0 + wn * 64 + n * 16 + c;
    bv[n] = bias[cc[n]];
  }
#pragma unroll
  for (int m = 0; m < 4; m++) {
    int rb = row0 + wm * 64 + m * 16 + (g << 2);
#pragma unroll
    for (int j = 0; j < 4; j++) {
      int r = rb + j;
      if (r < M) {
#pragma unroll
        for (int n = 0; n < 4; n++) {
          float vv = acc[m][n][j] + bv[n];
          size_t off = (size_t)r * N + cc[n];
          if constexpr (EPI == 0) {
            ((u16*)outp)[off] = f2b(vv);
          } else if constexpr (EPI == 1) {
            ((float*)outp)[off] = vv + res[off];
          } else {
            ((u16*)outp)[off] = f2b(gelu_exact(vv));
          }
        }
      }
    }
  }
}

// ---------------- CLS attention, flash-decode phase 1 ----------------
__global__ __launch_bounds__(256)
void cls_part(const u16* __restrict__ qkv, float* __restrict__ parts) {
  int bh = blockIdx.x;
  int chunk = blockIdx.y;
  int b = bh / kHeads, h = bh % kHeads;
  __shared__ float qs[32];
  __shared__ float ps[256];
  __shared__ float red[8];
  __shared__ float part[8][32];
  int tid = threadIdx.x, lane = tid & 63, wv = tid >> 6;
  size_t rb = (size_t)b * kL;
  if (tid < 32) qs[tid] = b2f(qkv[rb * 1152 + h * 32 + tid]) * kScale;
  __syncthreads();
  int t0 = chunk * 256;
  int nTok = min(256, kL - t0);
  float s = -1e30f;
  if (tid < nTok) {
    const u16* kp = qkv + (rb + t0 + tid) * 1152 + 384 + h * 32;
    s = 0.f;
#pragma unroll
    for (int g4 = 0; g4 < 4; g4++) {
      uint4 u = *(const uint4*)(kp + g4 * 8);
      s += qs[g4*8+0]*blo(u.x) + qs[g4*8+1]*bhi(u.x)
         + qs[g4*8+2]*blo(u.y) + qs[g4*8+3]*bhi(u.y)
         + qs[g4*8+4]*blo(u.z) + qs[g4*8+5]*bhi(u.z)
         + qs[g4*8+6]*blo(u.w) + qs[g4*8+7]*bhi(u.w);
    }
  }
  float m = wred_max(s);
  if (lane == 0) red[wv] = m;
  __syncthreads();
  float gm = fmaxf(fmaxf(red[0], red[1]), fmaxf(red[2], red[3]));
  float p = (tid < nTok) ? __expf(s - gm) : 0.f;
  ps[tid] = p;
  float ls = wred_sum(p);
  if (lane == 0) red[4 + wv] = ls;
  __syncthreads();
  float tot = red[4] + red[5] + red[6] + red[7];
  int d = tid & 31, g = tid >> 5;
  float a = 0.f;
  for (int t = g; t < nTok; t += 8)
    a += ps[t] * b2f(qkv[(rb + t0 + t) * 1152 + 768 + h * 32 + d]);
  part[g][d] = a;
  __syncthreads();
  if (tid < 32) {
    float o = 0.f;
#pragma unroll
    for (int g2 = 0; g2 < 8; g2++) o += part[g2][tid];
    float* pp = parts + ((size_t)bh * kNC + chunk) * 34;
    pp[2 + tid] = o;
    if (tid == 0) { pp[0] = gm; pp[1] = tot; }
  }
}

// ---------------- CLS attention, phase 2: LSE-merge 13 chunks ----------------
__global__ __launch_bounds__(64)
void cls_reduce(const float* __restrict__ parts, u16* __restrict__ aout) {
  int bh = blockIdx.x;
  int b = bh / kHeads, h = bh % kHeads;
  int tid = threadIdx.x;
  __shared__ float sm[kNC], ss[kNC];
  if (tid < kNC) {
    sm[tid] = parts[((size_t)bh * kNC + tid) * 34];
    ss[tid] = parts[((size_t)bh * kNC + tid) * 34 + 1];
  }
  __syncthreads();
  float M = -1e30f;
#pragma unroll
  for (int c = 0; c < kNC; c++) M = fmaxf(M, sm[c]);
  float W = 0.f;
#pragma unroll
  for (int c = 0; c < kNC; c++) W += ss[c] * __expf(sm[c] - M);
  if (tid < 32) {
    float o = 0.f;
#pragma unroll
    for (int c = 0; c < kNC; c++)
      o += parts[((size_t)bh * kNC + c) * 34 + 2 + tid] * __expf(sm[c] - M);
    aout[(size_t)b * kL * 384 + h * 32 + tid] = f2b(o / W);
  }
}

// ---------------- precompute bias_full[class][head][k][q] (64x64 per pair) ----------------
__global__ __launch_bounds__(256)
void bias_pre(const float* __restrict__ relb, float* __restrict__ bf) {
  int blk = blockIdx.x;           // cls*12 + h
  int cls = blk / 12, h = blk % 12;
  int clsH = (cls >> 1) & 1, clsW = cls & 1;
  for (int idx = threadIdx.x; idx < 4096; idx += 256) {
    int k = idx >> 6, q = idx & 63;
    float v = 0.f;
    if (k >= 50) {
      v = -1e9f;
    } else if (k >= 1 && q < 49) {
      int kt = k - 1, ki = kt / 7, kj = kt % 7;
      int qi = q / 7, qj = q % 7;
      v = relb[((qi - ki + 6) * 13 + (qj - kj + 6)) * 12 + h];
      int rq = (clsH ? (qi < 4 ? 1 : 2) : 0) * 3 + (clsW ? (qj < 4 ? 1 : 2) : 0);
      int rk = (clsH ? (ki < 4 ? 1 : 2) : 0) * 3 + (clsW ? (kj < 4 ? 1 : 2) : 0);
      if (rq != rk) v -= 100.f;
    }
    bf[(size_t)blk * 4096 + idx] = v;
  }
}

// ---------------- shifted-window attention, MFMA version ----------------
__global__ __launch_bounds__(256)
void win_attn2(const u16* __restrict__ qkv, const float* __restrict__ biasf,
               u16* __restrict__ aout) {
  const int tid = threadIdx.x, lane = tid & 63, wv = tid >> 6;
  const int gid = blockIdx.x * 4 + wv;
  const int h = gid % 12;
  const int wr = gid / 12;        // 0..2047
  const int win = wr & 63, b = wr >> 6;
  const int wi = win >> 3, wj = win & 7;
  const int cls = ((wi == 7) ? 2 : 0) + ((wj == 7) ? 1 : 0);
  const int c = lane & 15, g = lane >> 4;

  __shared__ __align__(16) u16 KS[4][64 * 40];   // K row-major, row stride 40 u16 (80B)
  __shared__ __align__(16) u16 VT[4][32 * 72];   // V transposed [d][tok], stride 72 u16
  __shared__ int RW[4][52];
  u16* Ks = KS[wv];
  u16* Vt = VT[wv];
  int* Rows = RW[wv];

#pragma unroll
  for (int it = 0; it < 2; ++it) {
    int idx = it * 64 + lane;
    int tok = idx >> 1, half = idx & 1;
    if (tok < 50) {
      int row;
      if (tok == 0) {
        row = b * kL;                                  // CLS
      } else {
        int n = tok - 1;
        int i = n / 7, j = n % 7;
        int r = wi * 7 + i, c2 = wj * 7 + j;           // rolled-canvas coords
        int orr = r + 3; if (orr >= 56) orr -= 56;     // original coords
        int occ = c2 + 3; if (occ >= 56) occ -= 56;
        row = b * kL + 1 + orr * 56 + occ;
      }
      if (half == 0) Rows[tok] = row;
      const u16* base = qkv + (size_t)row * 1152 + h * 32 + half * 16;
      uint4 k0 = *(const uint4*)(base + 384);
      uint4 k1 = *(const uint4*)(base + 384 + 8);
      *(uint4*)&Ks[tok * 40 + half * 16] = k0;
      *(uint4*)&Ks[tok * 40 + half * 16 + 8] = k1;
      uint4 v0 = *(const uint4*)(base + 768);
      uint4 v1 = *(const uint4*)(base + 768 + 8);
      u32 vw[8] = {v0.x, v0.y, v0.z, v0.w, v1.x, v1.y, v1.z, v1.w};
#pragma unroll
      for (int m = 0; m < 8; ++m) {
        Vt[(half * 16 + m * 2 + 0) * 72 + tok] = (u16)(vw[m] & 0xffffu);
        Vt[(half * 16 + m * 2 + 1) * 72 + tok] = (u16)(vw[m] >> 16);
      }
    } else {
      uint4 z = {0u, 0u, 0u, 0u};
      *(uint4*)&Ks[tok * 40 + half * 16] = z;
      *(uint4*)&Ks[tok * 40 + half * 16 + 8] = z;
#pragma unroll
      for (int m = 0; m < 16; ++m) Vt[(half * 16 + m) * 72 + tok] = 0;
    }
  }
  __syncthreads();

  bf16x8 qf[4];
#pragma unroll
  for (int nt = 0; nt < 4; ++nt) {
    int q = nt * 16 + c;
    if (q > 48) q = 48;
    const u16* qp = qkv + (size_t)Rows[q + 1] * 1152 + h * 32 + g * 8;
    qf[nt] = *(const bf16x8*)qp;
  }

  f32x4 s[4][4];
  {
    f32x4 z = {0.f, 0.f, 0.f, 0.f};
    bf16x8 kf[4];
#pragma unroll
    for (int mt = 0; mt < 4; ++mt)
      kf[mt] = *(const bf16x8*)&Ks[(mt * 16 + c) * 40 + g * 8];
#pragma unroll
    for (int mt = 0; mt < 4; ++mt)
#pragma unroll
      for (int nt = 0; nt < 4; ++nt)
        s[mt][nt] = __builtin_amdgcn_mfma_f32_16x16x32_bf16(kf[mt], qf[nt], z, 0, 0, 0);
  }

  const float* bp = biasf + (size_t)(cls * 12 + h) * 4096;
  u32 wq[4][8];
#pragma unroll
  for (int nt = 0; nt < 4; ++nt) {
    float pv[16];
#pragma unroll
    for (int mt = 0; mt < 4; ++mt)
#pragma unroll
      for (int r = 0; r < 4; ++r)
        pv[mt * 4 + r] = s[mt][nt][r] * kScale + bp[(mt * 16 + g * 4 + r) * 64 + nt * 16 + c];
    float mx = pv[0];
#pragma unroll
    for (int i2 = 1; i2 < 16; ++i2) mx = fmaxf(mx, pv[i2]);
    mx = fmaxf(mx, __shfl_xor(mx, 16));
    mx = fmaxf(mx, __shfl_xor(mx, 32));
    float sum = 0.f;
#pragma unroll
    for (int i2 = 0; i2 < 16; ++i2) { pv[i2] = __expf(pv[i2] - mx); sum += pv[i2]; }
    sum += __shfl_xor(sum, 16);
    sum += __shfl_xor(sum, 32);
    float rs = 1.f / sum;
#pragma unroll
    for (int i2 = 0; i2 < 16; ++i2) pv[i2] *= rs;
#pragma unroll
    for (int mt = 0; mt < 4; ++mt) {
      u32 w0, w1;
      asm("v_cvt_pk_bf16_f32 %0, %1, %2" : "=v"(w0) : "v"(pv[mt * 4 + 0]), "v"(pv[mt * 4 + 1]));
      asm("v_cvt_pk_bf16_f32 %0, %1, %2" : "=v"(w1) : "v"(pv[mt * 4 + 2]), "v"(pv[mt * 4 + 3]));
      wq[nt][mt * 2 + 0] = w0;
      wq[nt][mt * 2 + 1] = w1;
    }
  }

  bf16x8 pa[4][2];
#pragma unroll
  for (int mt2 = 0; mt2 < 4; ++mt2)
#pragma unroll
    for (int ks = 0; ks < 2; ++ks) {
      union { u32 u[4]; bf16x8 v; } cvt;
#pragma unroll
      for (int wj2 = 0; wj2 < 4; ++wj2) {
        int srcLane = c + 16 * (((g & 1) << 1) + (wj2 >> 1));
        u32 a0 = (u32)__shfl((int)wq[mt2][(2 * ks + 0) * 2 + (wj2 & 1)], srcLane);
        u32 a1 = (u32)__shfl((int)wq[mt2][(2 * ks + 1) * 2 + (wj2 & 1)], srcLane);
        cvt.u[wj2] = (g < 2) ? a0 : a1;
      }
      pa[mt2][ks] = cvt.v;
    }

  f32x4 o[4][2];
  f32x4 z2 = {0.f, 0.f, 0.f, 0.f};
#pragma unroll
  for (int mt2 = 0; mt2 < 4; ++mt2)
#pragma unroll
    for (int ntd = 0; ntd < 2; ++ntd) o[mt2][ntd] = z2;
#pragma unroll
  for (int ks = 0; ks < 2; ++ks) {
    bf16x8 vf[2];
#pragma unroll
    for (int ntd = 0; ntd < 2; ++ntd)
      vf[ntd] = *(const bf16x8*)&Vt[(ntd * 16 + c) * 72 + ks * 32 + g * 8];
#pragma unroll
    for (int mt2 = 0; mt2 < 4; ++mt2)
#pragma unroll
      for (int ntd = 0; ntd < 2; ++ntd)
        o[mt2][ntd] = __builtin_amdgcn_mfma_f32_16x16x32_bf16(pa[mt2][ks], vf[ntd], o[mt2][ntd], 0, 0, 0);
  }

#pragma unroll
  for (int mt2 = 0; mt2 < 4; ++mt2)
#pragma unroll
    for (int r = 0; r < 4; ++r) {
      int q = mt2 * 16 + g * 4 + r;
      if (q < 49) {
        int row = Rows[q + 1];
        u16* op = aout + (size_t)row * 384 + h * 32 + c;
        op[0]  = f2b(o[mt2][0][r]);
        op[16] = f2b(o[mt2][1][r]);
      }
    }
}

// ---------------- launcher ----------------
extern "C" void kernel_launch(void* const* d_in, const int* in_sizes, int n_in,
                              void* d_out, int out_size, void* d_ws, size_t ws_size,
                              hipStream_t stream) {
  const float* x      = (const float*)d_in[0];
  const float* n1g    = (const float*)d_in[1];
  const float* n1b    = (const float*)d_in[2];
  const float* qkv_w  = (const float*)d_in[3];
  const float* qkv_b  = (const float*)d_in[4];
  const float* relb   = (const float*)d_in[5];
  const float* proj_w = (const float*)d_in[6];
  const float* proj_b = (const float*)d_in[7];
  const float* n2g    = (const float*)d_in[8];
  const float* n2b    = (const float*)d_in[9];
  const float* fc1_w  = (const float*)d_in[10];
  const float* fc1_b  = (const float*)d_in[11];
  const float* fc2_w  = (const float*)d_in[12];
  const float* fc2_b  = (const float*)d_in[13];
  float* out = (float*)d_out;
  char* ws = (char*)d_ws;

  // workspace layout (total ~312 MB); x1 lives in d_out
  u16* wqkv  = (u16*)(ws + 0);                       //  884,736 B (dead after qkv GEMM)
  float* biasf = (float*)(ws + 0);                   //  786,432 B (reuses wqkv region)
  u16* wproj = (u16*)(ws + 884736);                  //  294,912 B
  u16* wfc1  = (u16*)(ws + 1179648);                 // 1,179,648 B
  u16* wfc2  = (u16*)(ws + 2359296);                 // 1,179,648 B
  u16* qkvb  = (u16*)(ws + 3538944);                 // 231,284,736 B (dead after attention)
  u16* h2b   = (u16*)(ws + 3538944);                 // reuse: LN2 chunk out (38.5 MB)
  u16* gb    = (u16*)(ws + 3538944 + 41943040);      // reuse: fc1 chunk out (154.2 MB)
  u16* hbuf  = (u16*)(ws + 234823680);               // 77,094,912 B (h, then attn_out)
  float* parts = (float*)d_out;                      // CLS partials: dead-until-proj d_out

  cvt_bf16<<<dim3((442368 + 255) / 256), 256, 0, stream>>>(qkv_w, wqkv, 442368);
  cvt_bf16<<<dim3((147456 + 255) / 256), 256, 0, stream>>>(proj_w, wproj, 147456);
  cvt_bf16<<<dim3((589824 + 255) / 256), 256, 0, stream>>>(fc1_w, wfc1, 589824);
  cvt_bf16<<<dim3((589824 + 255) / 256), 256, 0, stream>>>(fc2_w, wfc2, 589824);

  ln384<<<(kM + 3) / 4, 256, 0, stream>>>(x, n1g, n1b, hbuf, kM);
  gemm_bt<0><<<9 * 785, 256, 0, stream>>>(hbuf, wqkv, qkv_b, nullptr, qkvb, kM, 1152, 384, 9);
  bias_pre<<<48, 256, 0, stream>>>(relb, biasf);     // into dead wqkv region
  cls_part<<<dim3(kB * kHeads, kNC), 256, 0, stream>>>(qkvb, parts);
  cls_reduce<<<kB * kHeads, 64, 0, stream>>>(parts, hbuf);
  win_attn2<<<kB * 64 * kHeads / 4, 256, 0, stream>>>(qkvb, biasf, hbuf);
  gemm_bt<1><<<3 * 785, 256, 0, stream>>>(hbuf, wproj, proj_b, x, out, kM, 384, 384, 3);

  for (int c = 0; c < 2; c++) {
    int r0 = c * 50192, nr = 50192;
    ln384<<<(nr + 3) / 4, 256, 0, stream>>>(out + (size_t)r0 * 384, n2g, n2b, h2b, nr);
    gemm_bt<2><<<12 * 393, 256, 0, stream>>>(h2b, wfc1, fc1_b, nullptr, gb, nr, 1536, 384, 12);
    gemm_bt<1><<<3 * 393, 256, 0, stream>>>(gb, wfc2, fc2_b, out + (size_t)r0 * 384,
                                            out + (size_t)r0 * 384, nr, 384, 1536, 3);
  }
}

// Round 10
// 1004.106 us; speedup vs baseline: 1.3316x; 1.0134x over previous
//
#include <hip/hip_runtime.h>

#define DEVI __device__ __forceinline__

typedef __attribute__((ext_vector_type(8))) __bf16 bf16x8;
typedef __attribute__((ext_vector_type(4))) float f32x4;
typedef unsigned short u16;
typedef unsigned int u32;

static constexpr int kB = 32;
static constexpr int kL = 3137;           // 56*56+1
static constexpr int kM = kB * kL;        // 100384 rows total
static constexpr int kHeads = 12;
static constexpr float kScale = 0.17677669529663687f;  // 32^-0.5
static constexpr int kNC = 13;            // CLS key chunks of 256 (13*256 >= 3137)

DEVI u16 f2b(float f) {                   // f32 -> bf16 RNE
  u32 u = __float_as_uint(f);
  u32 r = (u + 0x7fffu + ((u >> 16) & 1u)) >> 16;
  return (u16)r;
}
DEVI float blo(u32 u) { return __uint_as_float(u << 16); }
DEVI float bhi(u32 u) { return __uint_as_float(u & 0xffff0000u); }
DEVI float b2f(u16 h) { return __uint_as_float(((u32)h) << 16); }

DEVI void async16(const void* g, void* l) {
  __builtin_amdgcn_global_load_lds((const __attribute__((address_space(1))) u32*)g,
                                   (__attribute__((address_space(3))) u32*)l, 16, 0, 0);
}

DEVI float wred_max(float v) {
#pragma unroll
  for (int o = 32; o; o >>= 1) v = fmaxf(v, __shfl_xor(v, o));
  return v;
}
DEVI float wred_sum(float v) {
#pragma unroll
  for (int o = 32; o; o >>= 1) v += __shfl_xor(v, o);
  return v;
}

// ---------------- all-weights f32 -> bf16, single launch ----------------
// segments: qkv 442368 | proj 147456 | fc1 589824 | fc2 589824  (cum 1769472)
__global__ void cvt_all(const float* __restrict__ a, const float* __restrict__ b,
                        const float* __restrict__ c2, const float* __restrict__ d,
                        u16* __restrict__ oa, u16* __restrict__ ob,
                        u16* __restrict__ oc, u16* __restrict__ od) {
  int i = blockIdx.x * 256 + threadIdx.x;
  if (i < 442368) oa[i] = f2b(a[i]);
  else if (i < 589824) ob[i - 442368] = f2b(b[i - 442368]);
  else if (i < 1179648) oc[i - 589824] = f2b(c2[i - 589824]);
  else od[i - 1179648] = f2b(d[i - 1179648]);
}

// ---------------- LayerNorm over 384: 4 rows/block, wave per row, float2 vec ----------------
__global__ __launch_bounds__(256)
void ln384(const float* __restrict__ x, const float* __restrict__ gam,
           const float* __restrict__ bet, u16* __restrict__ out, int rows) {
  int row = blockIdx.x * 4 + (threadIdx.x >> 6);
  if (row >= rows) return;
  int lane = threadIdx.x & 63;
  const float2* xr = (const float2*)(x + (size_t)row * 384);
  float2 v[3];
  float s = 0.f, s2 = 0.f;
#pragma unroll
  for (int i = 0; i < 3; i++) {
    v[i] = xr[lane + 64 * i];
    s += v[i].x + v[i].y;
    s2 += v[i].x * v[i].x + v[i].y * v[i].y;
  }
  s = wred_sum(s);
  s2 = wred_sum(s2);
  float mean = s * (1.f / 384.f);
  float var = s2 * (1.f / 384.f) - mean * mean;
  float rinv = rsqrtf(var + 1e-5f);
  const float2* gp = (const float2*)gam;
  const float2* bp = (const float2*)bet;
  u32* orow = (u32*)(out + (size_t)row * 384);
#pragma unroll
  for (int i = 0; i < 3; i++) {
    int idx = lane + 64 * i;
    float2 gg = gp[idx], bb = bp[idx];
    float lo = (v[i].x - mean) * rinv * gg.x + bb.x;
    float hi = (v[i].y - mean) * rinv * gg.y + bb.y;
    orow[idx] = (u32)f2b(lo) | ((u32)f2b(hi) << 16);
  }
}

DEVI float gelu_exact(float v) { return 0.5f * v * (1.f + erff(v * 0.70710678118654752f)); }

// ---------------- bf16 MFMA GEMM, multi-M-tile (prologue-amortized) ----------------
// Benched-best R3/R4 K-loop (128x128 tile, BK=32, 3-buf LDS, counted vmcnt(4),
// proven zero-conflict swizzle pair, XCD swizzle, setprio) extended so each block
// processes TMv consecutive row-tiles in one column strip as a FLAT phase stream:
// stage(ph+2) rolls across tile boundaries, so the HBM prologue is paid once per
// block and each tile's epilogue overlaps the next tile's in-flight loads.
// Ledger: in-flight before each wait = 8 (phases ph, ph+1); vmcnt(4) -> phase ph
// landed; vmcnt(0) only at the global last phase. Buffer rotation cur/(cur+2)%3
// identical to R3 (stage target's last readers ran >=2 barriers upstream).
// EPI: 0 = bias -> bf16 ; 1 = bias + res -> f32 ; 2 = bias + gelu -> bf16
template <int EPI>
__global__ __launch_bounds__(256)
void gemm_bt(const u16* __restrict__ A, const u16* __restrict__ W,
             const float* __restrict__ bias, const float* __restrict__ res,
             void* __restrict__ outp, int M, int N, int K, int NX, int TMv) {
  // T1: bijective XCD swizzle (m204) on flattened 1D grid
  const int nwg = gridDim.x;
  const int orig = blockIdx.x;
  const int xcd = orig & 7, rest = orig >> 3;
  const int q8 = nwg >> 3, r8 = nwg & 7;
  const int id = ((xcd < r8) ? xcd * (q8 + 1) : r8 * (q8 + 1) + (xcd - r8) * q8) + rest;
  const int col0 = (id % NX) * 128;
  const int rowG = (id / NX) * TMv * 128;        // block's row-group base

  const int tid = threadIdx.x, lane = tid & 63, wv = tid >> 6;
  __shared__ __align__(16) u16 As[3][128 * 32];
  __shared__ __align__(16) u16 Bs[3][128 * 32];
  const int wm = wv >> 1, wn = wv & 1;
  const int c = lane & 15, g = lane >> 4;
  const int NT = K >> 5;

  const int rr = lane >> 2;
  const int gnat = (lane & 3) ^ ((lane >> 3) & 3);     // proven source pre-swizzle

  auto stage = [&](int t2, int k2, int bfi) {
    int kk = k2 * 32 + gnat * 8;
    int rbase = rowG + t2 * 128;
#pragma unroll
    for (int s = 0; s < 2; s++) {
      int ch = wv * 2 + s;                             // 8 chunks of 16 rows x 64B
      int r = ch * 16 + rr;
      async16(A + (size_t)min(rbase + r, M - 1) * K + kk, &As[bfi][ch * 512]);
      async16(W + (size_t)min(col0 + r, N - 1) * K + kk, &Bs[bfi][ch * 512]);
    }
  };

  int cc[4];
  float bv[4];
#pragma unroll
  for (int n = 0; n < 4; n++) {
    cc[n] = col0 + wn * 64 + n * 16 + c;
    bv[n] = bias[cc[n]];
  }

  stage(0, 0, 0);                                      // prologue: 8 in flight
  stage(0, 1, 1);
  int cur = 0;
  for (int t = 0; t < TMv; ++t) {
    f32x4 acc[4][4];
    f32x4 zero = {0.f, 0.f, 0.f, 0.f};
#pragma unroll
    for (int m = 0; m < 4; m++)
#pragma unroll
      for (int n = 0; n < 4; n++) acc[m][n] = zero;

    for (int kt = 0; kt < NT; ++kt) {
      if (t == TMv - 1 && kt == NT - 1) asm volatile("s_waitcnt vmcnt(0)" ::: "memory");
      else                              asm volatile("s_waitcnt vmcnt(4)" ::: "memory");
      __builtin_amdgcn_s_barrier();                    // all waves' phase loads landed
      {
        int kt2 = kt + 2, t2 = t;
        if (kt2 >= NT) { kt2 -= NT; t2++; }
        if (t2 < TMv) {
          int nb = cur + 2; if (nb >= 3) nb -= 3;
          stage(t2, kt2, nb);
        }
      }
      bf16x8 af[4], bw[4];
#pragma unroll
      for (int m = 0; m < 4; m++) {
        int row = wm * 64 + m * 16 + c;
        af[m] = *(const bf16x8*)&As[cur][row * 32 + ((g ^ ((row >> 1) & 3)) << 3)];
      }
#pragma unroll
      for (int n = 0; n < 4; n++) {
        int row = wn * 64 + n * 16 + c;
        bw[n] = *(const bf16x8*)&Bs[cur][row * 32 + ((g ^ ((row >> 1) & 3)) << 3)];
      }
      __builtin_amdgcn_s_setprio(1);
#pragma unroll
      for (int m = 0; m < 4; m++)
#pragma unroll
        for (int n = 0; n < 4; n++)
          acc[m][n] = __builtin_amdgcn_mfma_f32_16x16x32_bf16(af[m], bw[n], acc[m][n], 0, 0, 0);
      __builtin_amdgcn_s_setprio(0);
      cur = cur + 1; if (cur >= 3) cur -= 3;
    }

    // epilogue for tile t (overlaps next tile's in-flight staging)
    int rowT = rowG + t * 128;
#pragma unroll
    for (int m = 0; m < 4; m++) {
      int rb = rowT + wm * 64 + m * 16 + (g << 2);
#pragma unroll
      for (int j = 0; j < 4; j++) {
        int r = rb + j;
        if (r < M) {
#pragma unroll
          for (int n = 0; n < 4; n++) {
            float vv = acc[m][n][j] + bv[n];
            size_t off = (size_t)r * N + cc[n];
            if constexpr (EPI == 0) {
              ((u16*)outp)[off] = f2b(vv);
            } else if constexpr (EPI == 1) {
              ((float*)outp)[off] = vv + res[off];
            } else {
              ((u16*)outp)[off] = f2b(gelu_exact(vv));
            }
          }
        }
      }
    }
  }
}

// ---------------- CLS attention, flash-decode phase 1 ----------------
__global__ __launch_bounds__(256)
void cls_part(const u16* __restrict__ qkv, float* __restrict__ parts) {
  int bh = blockIdx.x;
  int chunk = blockIdx.y;
  int b = bh / kHeads, h = bh % kHeads;
  __shared__ float qs[32];
  __shared__ float ps[256];
  __shared__ float red[8];
  __shared__ float part[8][32];
  int tid = threadIdx.x, lane = tid & 63, wv = tid >> 6;
  size_t rb = (size_t)b * kL;
  if (tid < 32) qs[tid] = b2f(qkv[rb * 1152 + h * 32 + tid]) * kScale;
  __syncthreads();
  int t0 = chunk * 256;
  int nTok = min(256, kL - t0);
  float s = -1e30f;
  if (tid < nTok) {
    const u16* kp = qkv + (rb + t0 + tid) * 1152 + 384 + h * 32;
    s = 0.f;
#pragma unroll
    for (int g4 = 0; g4 < 4; g4++) {
      uint4 u = *(const uint4*)(kp + g4 * 8);
      s += qs[g4*8+0]*blo(u.x) + qs[g4*8+1]*bhi(u.x)
         + qs[g4*8+2]*blo(u.y) + qs[g4*8+3]*bhi(u.y)
         + qs[g4*8+4]*blo(u.z) + qs[g4*8+5]*bhi(u.z)
         + qs[g4*8+6]*blo(u.w) + qs[g4*8+7]*bhi(u.w);
    }
  }
  float m = wred_max(s);
  if (lane == 0) red[wv] = m;
  __syncthreads();
  float gm = fmaxf(fmaxf(red[0], red[1]), fmaxf(red[2], red[3]));
  float p = (tid < nTok) ? __expf(s - gm) : 0.f;
  ps[tid] = p;
  float ls = wred_sum(p);
  if (lane == 0) red[4 + wv] = ls;
  __syncthreads();
  float tot = red[4] + red[5] + red[6] + red[7];
  int d = tid & 31, g = tid >> 5;
  float a = 0.f;
  for (int t = g; t < nTok; t += 8)
    a += ps[t] * b2f(qkv[(rb + t0 + t) * 1152 + 768 + h * 32 + d]);
  part[g][d] = a;
  __syncthreads();
  if (tid < 32) {
    float o = 0.f;
#pragma unroll
    for (int g2 = 0; g2 < 8; g2++) o += part[g2][tid];
    float* pp = parts + ((size_t)bh * kNC + chunk) * 34;
    pp[2 + tid] = o;
    if (tid == 0) { pp[0] = gm; pp[1] = tot; }
  }
}

// ---------------- CLS attention, phase 2: LSE-merge 13 chunks ----------------
__global__ __launch_bounds__(64)
void cls_reduce(const float* __restrict__ parts, u16* __restrict__ aout) {
  int bh = blockIdx.x;
  int b = bh / kHeads, h = bh % kHeads;
  int tid = threadIdx.x;
  __shared__ float sm[kNC], ss[kNC];
  if (tid < kNC) {
    sm[tid] = parts[((size_t)bh * kNC + tid) * 34];
    ss[tid] = parts[((size_t)bh * kNC + tid) * 34 + 1];
  }
  __syncthreads();
  float M = -1e30f;
#pragma unroll
  for (int c = 0; c < kNC; c++) M = fmaxf(M, sm[c]);
  float W = 0.f;
#pragma unroll
  for (int c = 0; c < kNC; c++) W += ss[c] * __expf(sm[c] - M);
  if (tid < 32) {
    float o = 0.f;
#pragma unroll
    for (int c = 0; c < kNC; c++)
      o += parts[((size_t)bh * kNC + c) * 34 + 2 + tid] * __expf(sm[c] - M);
    aout[(size_t)b * kL * 384 + h * 32 + tid] = f2b(o / W);
  }
}

// ---------------- precompute bias_full[class][head][k][q] (64x64 per pair) ----------------
__global__ __launch_bounds__(256)
void bias_pre(const float* __restrict__ relb, float* __restrict__ bf) {
  int blk = blockIdx.x;           // cls*12 + h
  int cls = blk / 12, h = blk % 12;
  int clsH = (cls >> 1) & 1, clsW = cls & 1;
  for (int idx = threadIdx.x; idx < 4096; idx += 256) {
    int k = idx >> 6, q = idx & 63;
    float v = 0.f;
    if (k >= 50) {
      v = -1e9f;
    } else if (k >= 1 && q < 49) {
      int kt = k - 1, ki = kt / 7, kj = kt % 7;
      int qi = q / 7, qj = q % 7;
      v = relb[((qi - ki + 6) * 13 + (qj - kj + 6)) * 12 + h];
      int rq = (clsH ? (qi < 4 ? 1 : 2) : 0) * 3 + (clsW ? (qj < 4 ? 1 : 2) : 0);
      int rk = (clsH ? (ki < 4 ? 1 : 2) : 0) * 3 + (clsW ? (kj < 4 ? 1 : 2) : 0);
      if (rq != rk) v -= 100.f;
    }
    bf[(size_t)blk * 4096 + idx] = v;
  }
}

// ---------------- shifted-window attention, MFMA version ----------------
__global__ __launch_bounds__(256)
void win_attn2(const u16* __restrict__ qkv, const float* __restrict__ biasf,
               u16* __restrict__ aout) {
  const int tid = threadIdx.x, lane = tid & 63, wv = tid >> 6;
  const int gid = blockIdx.x * 4 + wv;
  const int h = gid % 12;
  const int wr = gid / 12;        // 0..2047
  const int win = wr & 63, b = wr >> 6;
  const int wi = win >> 3, wj = win & 7;
  const int cls = ((wi == 7) ? 2 : 0) + ((wj == 7) ? 1 : 0);
  const int c = lane & 15, g = lane >> 4;

  __shared__ __align__(16) u16 KS[4][64 * 40];   // K row-major, row stride 40 u16 (80B)
  __shared__ __align__(16) u16 VT[4][32 * 72];   // V transposed [d][tok], stride 72 u16
  __shared__ int RW[4][52];
  u16* Ks = KS[wv];
  u16* Vt = VT[wv];
  int* Rows = RW[wv];

#pragma unroll
  for (int it = 0; it < 2; ++it) {
    int idx = it * 64 + lane;
    int tok = idx >> 1, half = idx & 1;
    if (tok < 50) {
      int row;
      if (tok == 0) {
        row = b * kL;                                  // CLS
      } else {
        int n = tok - 1;
        int i = n / 7, j = n % 7;
        int r = wi * 7 + i, c2 = wj * 7 + j;           // rolled-canvas coords
        int orr = r + 3; if (orr >= 56) orr -= 56;     // original coords
        int occ = c2 + 3; if (occ >= 56) occ -= 56;
        row = b * kL + 1 + orr * 56 + occ;
      }
      if (half == 0) Rows[tok] = row;
      const u16* base = qkv + (size_t)row * 1152 + h * 32 + half * 16;
      uint4 k0 = *(const uint4*)(base + 384);
      uint4 k1 = *(const uint4*)(base + 384 + 8);
      *(uint4*)&Ks[tok * 40 + half * 16] = k0;
      *(uint4*)&Ks[tok * 40 + half * 16 + 8] = k1;
      uint4 v0 = *(const uint4*)(base + 768);
      uint4 v1 = *(const uint4*)(base + 768 + 8);
      u32 vw[8] = {v0.x, v0.y, v0.z, v0.w, v1.x, v1.y, v1.z, v1.w};
#pragma unroll
      for (int m = 0; m < 8; ++m) {
        Vt[(half * 16 + m * 2 + 0) * 72 + tok] = (u16)(vw[m] & 0xffffu);
        Vt[(half * 16 + m * 2 + 1) * 72 + tok] = (u16)(vw[m] >> 16);
      }
    } else {
      uint4 z = {0u, 0u, 0u, 0u};
      *(uint4*)&Ks[tok * 40 + half * 16] = z;
      *(uint4*)&Ks[tok * 40 + half * 16 + 8] = z;
#pragma unroll
      for (int m = 0; m < 16; ++m) Vt[(half * 16 + m) * 72 + tok] = 0;
    }
  }
  __syncthreads();

  bf16x8 qf[4];
#pragma unroll
  for (int nt = 0; nt < 4; ++nt) {
    int q = nt * 16 + c;
    if (q > 48) q = 48;
    const u16* qp = qkv + (size_t)Rows[q + 1] * 1152 + h * 32 + g * 8;
    qf[nt] = *(const bf16x8*)qp;
  }

  f32x4 s[4][4];
  {
    f32x4 z = {0.f, 0.f, 0.f, 0.f};
    bf16x8 kf[4];
#pragma unroll
    for (int mt = 0; mt < 4; ++mt)
      kf[mt] = *(const bf16x8*)&Ks[(mt * 16 + c) * 40 + g * 8];
#pragma unroll
    for (int mt = 0; mt < 4; ++mt)
#pragma unroll
      for (int nt = 0; nt < 4; ++nt)
        s[mt][nt] = __builtin_amdgcn_mfma_f32_16x16x32_bf16(kf[mt], qf[nt], z, 0, 0, 0);
  }

  const float* bp = biasf + (size_t)(cls * 12 + h) * 4096;
  u32 wq[4][8];
#pragma unroll
  for (int nt = 0; nt < 4; ++nt) {
    float pv[16];
#pragma unroll
    for (int mt = 0; mt < 4; ++mt)
#pragma unroll
      for (int r = 0; r < 4; ++r)
        pv[mt * 4 + r] = s[mt][nt][r] * kScale + bp[(mt * 16 + g * 4 + r) * 64 + nt * 16 + c];
    float mx = pv[0];
#pragma unroll
    for (int i2 = 1; i2 < 16; ++i2) mx = fmaxf(mx, pv[i2]);
    mx = fmaxf(mx, __shfl_xor(mx, 16));
    mx = fmaxf(mx, __shfl_xor(mx, 32));
    float sum = 0.f;
#pragma unroll
    for (int i2 = 0; i2 < 16; ++i2) { pv[i2] = __expf(pv[i2] - mx); sum += pv[i2]; }
    sum += __shfl_xor(sum, 16);
    sum += __shfl_xor(sum, 32);
    float rs = 1.f / sum;
#pragma unroll
    for (int i2 = 0; i2 < 16; ++i2) pv[i2] *= rs;
#pragma unroll
    for (int mt = 0; mt < 4; ++mt) {
      u32 w0, w1;
      asm("v_cvt_pk_bf16_f32 %0, %1, %2" : "=v"(w0) : "v"(pv[mt * 4 + 0]), "v"(pv[mt * 4 + 1]));
      asm("v_cvt_pk_bf16_f32 %0, %1, %2" : "=v"(w1) : "v"(pv[mt * 4 + 2]), "v"(pv[mt * 4 + 3]));
      wq[nt][mt * 2 + 0] = w0;
      wq[nt][mt * 2 + 1] = w1;
    }
  }

  bf16x8 pa[4][2];
#pragma unroll
  for (int mt2 = 0; mt2 < 4; ++mt2)
#pragma unroll
    for (int ks = 0; ks < 2; ++ks) {
      union { u32 u[4]; bf16x8 v; } cvt;
#pragma unroll
      for (int wj2 = 0; wj2 < 4; ++wj2) {
        int srcLane = c + 16 * (((g & 1) << 1) + (wj2 >> 1));
        u32 a0 = (u32)__shfl((int)wq[mt2][(2 * ks + 0) * 2 + (wj2 & 1)], srcLane);
        u32 a1 = (u32)__shfl((int)wq[mt2][(2 * ks + 1) * 2 + (wj2 & 1)], srcLane);
        cvt.u[wj2] = (g < 2) ? a0 : a1;
      }
      pa[mt2][ks] = cvt.v;
    }

  f32x4 o[4][2];
  f32x4 z2 = {0.f, 0.f, 0.f, 0.f};
#pragma unroll
  for (int mt2 = 0; mt2 < 4; ++mt2)
#pragma unroll
    for (int ntd = 0; ntd < 2; ++ntd) o[mt2][ntd] = z2;
#pragma unroll
  for (int ks = 0; ks < 2; ++ks) {
    bf16x8 vf[2];
#pragma unroll
    for (int ntd = 0; ntd < 2; ++ntd)
      vf[ntd] = *(const bf16x8*)&Vt[(ntd * 16 + c) * 72 + ks * 32 + g * 8];
#pragma unroll
    for (int mt2 = 0; mt2 < 4; ++mt2)
#pragma unroll
      for (int ntd = 0; ntd < 2; ++ntd)
        o[mt2][ntd] = __builtin_amdgcn_mfma_f32_16x16x32_bf16(pa[mt2][ks], vf[ntd], o[mt2][ntd], 0, 0, 0);
  }

#pragma unroll
  for (int mt2 = 0; mt2 < 4; ++mt2)
#pragma unroll
    for (int r = 0; r < 4; ++r) {
      int q = mt2 * 16 + g * 4 + r;
      if (q < 49) {
        int row = Rows[q + 1];
        u16* op = aout + (size_t)row * 384 + h * 32 + c;
        op[0]  = f2b(o[mt2][0][r]);
        op[16] = f2b(o[mt2][1][r]);
      }
    }
}

// ---------------- launcher ----------------
extern "C" void kernel_launch(void* const* d_in, const int* in_sizes, int n_in,
                              void* d_out, int out_size, void* d_ws, size_t ws_size,
                              hipStream_t stream) {
  const float* x      = (const float*)d_in[0];
  const float* n1g    = (const float*)d_in[1];
  const float* n1b    = (const float*)d_in[2];
  const float* qkv_w  = (const float*)d_in[3];
  const float* qkv_b  = (const float*)d_in[4];
  const float* relb   = (const float*)d_in[5];
  const float* proj_w = (const float*)d_in[6];
  const float* proj_b = (const float*)d_in[7];
  const float* n2g    = (const float*)d_in[8];
  const float* n2b    = (const float*)d_in[9];
  const float* fc1_w  = (const float*)d_in[10];
  const float* fc1_b  = (const float*)d_in[11];
  const float* fc2_w  = (const float*)d_in[12];
  const float* fc2_b  = (const float*)d_in[13];
  float* out = (float*)d_out;
  char* ws = (char*)d_ws;

  // workspace layout (total ~312 MB); x1 lives in d_out
  u16* wqkv  = (u16*)(ws + 0);                       //  884,736 B (dead after qkv GEMM)
  float* biasf = (float*)(ws + 0);                   //  786,432 B (reuses wqkv region)
  u16* wproj = (u16*)(ws + 884736);                  //  294,912 B
  u16* wfc1  = (u16*)(ws + 1179648);                 // 1,179,648 B
  u16* wfc2  = (u16*)(ws + 2359296);                 // 1,179,648 B
  u16* qkvb  = (u16*)(ws + 3538944);                 // 231,284,736 B (dead after attention)
  u16* h2b   = (u16*)(ws + 3538944);                 // reuse: LN2 chunk out (38.5 MB)
  u16* gb    = (u16*)(ws + 3538944 + 41943040);      // reuse: fc1 chunk out (154.2 MB)
  u16* hbuf  = (u16*)(ws + 234823680);               // 77,094,912 B (h, then attn_out)
  float* parts = (float*)d_out;                      // CLS partials: dead-until-proj d_out

  cvt_all<<<6912, 256, 0, stream>>>(qkv_w, proj_w, fc1_w, fc2_w, wqkv, wproj, wfc1, wfc2);

  ln384<<<(kM + 3) / 4, 256, 0, stream>>>(x, n1g, n1b, hbuf, kM);
  // qkv: 785 row-tiles, TM=4 -> 197 groups x 9 col strips
  gemm_bt<0><<<9 * 197, 256, 0, stream>>>(hbuf, wqkv, qkv_b, nullptr, qkvb, kM, 1152, 384, 9, 4);
  bias_pre<<<48, 256, 0, stream>>>(relb, biasf);     // into dead wqkv region
  cls_part<<<dim3(kB * kHeads, kNC), 256, 0, stream>>>(qkvb, parts);
  cls_reduce<<<kB * kHeads, 64, 0, stream>>>(parts, hbuf);
  win_attn2<<<kB * 64 * kHeads / 4, 256, 0, stream>>>(qkvb, biasf, hbuf);
  // proj: 785 row-tiles, TM=2 -> 393 groups x 3 strips
  gemm_bt<1><<<3 * 393, 256, 0, stream>>>(hbuf, wproj, proj_b, x, out, kM, 384, 384, 3, 2);

  for (int c = 0; c < 2; c++) {
    int r0 = c * 50192, nr = 50192;
    ln384<<<(nr + 3) / 4, 256, 0, stream>>>(out + (size_t)r0 * 384, n2g, n2b, h2b, nr);
    // fc1: 393 row-tiles, TM=4 -> 99 groups x 12 strips
    gemm_bt<2><<<12 * 99, 256, 0, stream>>>(h2b, wfc1, fc1_b, nullptr, gb, nr, 1536, 384, 12, 4);
    // fc2: K=1536 already amortized -> TM=1
    gemm_bt<1><<<3 * 393, 256, 0, stream>>>(gb, wfc2, fc2_b, out + (size_t)r0 * 384,
                                            out + (size_t)r0 * 384, nr, 384, 1536, 3, 1);
  }
}